// Round 3
// baseline (296.479 us; speedup 1.0000x reference)
//
#include <hip/hip_runtime.h>
#include <hip/hip_bf16.h>

#define B_N 32
#define SX 2048
#define SY 512
#define DIM 1024
#define NTOK 2
#define DN 128
#define ODIM 1024
#define BM 64

typedef __bf16 bf16;
typedef __bf16 bf16x8 __attribute__((ext_vector_type(8)));
typedef __bf16 bf16x2 __attribute__((ext_vector_type(2)));
typedef float f32x4 __attribute__((ext_vector_type(4)));

__device__ __forceinline__ f32x4 mfma16(bf16x8 a, bf16x8 b, f32x4 c) {
  return __builtin_amdgcn_mfma_f32_16x16x32_bf16(a, b, c, 0, 0, 0);
}

// Convert weights fp32 -> bf16 once per call (weights are small, L2-resident).
__global__ __launch_bounds__(256) void prep_kernel(const float* __restrict__ Wd,
                                                   const float* __restrict__ Wu,
                                                   bf16* __restrict__ wdb,
                                                   bf16* __restrict__ wub) {
  int i = blockIdx.x * 256 + threadIdx.x;
  if (i < DN * DIM) {
    wdb[i] = (bf16)Wd[i];
    wub[i] = (bf16)Wu[i];
  }
}

// tokens[b,t,:] = latent[t] + sum_s softmax_s(latent[t].y[b,s]) * y[b,s]
// Only needed when gate != 0 (slow path; bench has gate == 0).
__global__ __launch_bounds__(256) void tokens_kernel(const float* __restrict__ y,
                                                     const float* __restrict__ lat,
                                                     const float* __restrict__ gate,
                                                     float* __restrict__ tokens) {
  if (gate[0] == 0.0f) return;  // output is independent of tokens in that case
  __shared__ float s_lat[NTOK][DIM];
  __shared__ float s_sc[NTOK][SY];
  int b = blockIdx.x;
  int tid = threadIdx.x, wave = tid >> 6, lane = tid & 63;
  const float* yb = y + (size_t)b * SY * DIM;
  for (int i = tid; i < NTOK * DIM; i += 256) ((float*)s_lat)[i] = lat[i];
  __syncthreads();
  for (int s = wave * 128; s < wave * 128 + 128; ++s) {
    const float* yr = yb + (size_t)s * DIM;
    float d0 = 0.f, d1 = 0.f;
#pragma unroll
    for (int i = 0; i < 4; ++i) {
      f32x4 v = *(const f32x4*)(yr + lane * 4 + i * 256);
      f32x4 l0 = *(const f32x4*)(&s_lat[0][lane * 4 + i * 256]);
      f32x4 l1 = *(const f32x4*)(&s_lat[1][lane * 4 + i * 256]);
      d0 += v[0] * l0[0] + v[1] * l0[1] + v[2] * l0[2] + v[3] * l0[3];
      d1 += v[0] * l1[0] + v[1] * l1[1] + v[2] * l1[2] + v[3] * l1[3];
    }
#pragma unroll
    for (int off = 32; off > 0; off >>= 1) {
      d0 += __shfl_xor(d0, off);
      d1 += __shfl_xor(d1, off);
    }
    if (lane == 0) { s_sc[0][s] = d0; s_sc[1][s] = d1; }
  }
  __syncthreads();
  if (wave < 2) {
    float m = -3.4e38f;
    for (int s = lane; s < SY; s += 64) m = fmaxf(m, s_sc[wave][s]);
#pragma unroll
    for (int off = 32; off > 0; off >>= 1) m = fmaxf(m, __shfl_xor(m, off));
    float sum = 0.f;
    for (int s = lane; s < SY; s += 64) {
      float e = expf(s_sc[wave][s] - m);
      s_sc[wave][s] = e;
      sum += e;
    }
#pragma unroll
    for (int off = 32; off > 0; off >>= 1) sum += __shfl_xor(sum, off);
    float inv = 1.f / sum;
    for (int s = lane; s < SY; s += 64) s_sc[wave][s] *= inv;
  }
  __syncthreads();
  float a0[4] = {0.f, 0.f, 0.f, 0.f}, a1[4] = {0.f, 0.f, 0.f, 0.f};
  for (int s = 0; s < SY; ++s) {
    float p0 = s_sc[0][s], p1 = s_sc[1][s];
    const float* yr = yb + (size_t)s * DIM;
#pragma unroll
    for (int i = 0; i < 4; ++i) {
      float v = yr[tid + i * 256];
      a0[i] += p0 * v;
      a1[i] += p1 * v;
    }
  }
  float* tb = tokens + (size_t)b * NTOK * DIM;
#pragma unroll
  for (int i = 0; i < 4; ++i) {
    tb[tid + i * 256] = s_lat[0][tid + i * 256] + a0[i];
    tb[DIM + tid + i * 256] = s_lat[1][tid + i * 256] + a1[i];
  }
}

// Barrier-free fused kernel. Each wave owns 16 rows of x end-to-end:
//   GEMM1 (transposed): Z^T = Wd . x'^T  -- B-frag of mfma is a direct
//   coalesced global load of x (no LDS staging, no syncthreads).
//   ReLU -> bf16 -> private per-wave swizzled LDS tile (wave-local, no barrier).
//   GEMM2 (transposed): out^T = Wu . Z^T -> packed f32x4 stores.
__global__ __launch_bounds__(256, 4) void main_kernel(const float* __restrict__ x,
                                                      const float* __restrict__ gate,
                                                      const float* __restrict__ tokens,
                                                      const bf16* __restrict__ wdb,
                                                      const bf16* __restrict__ wub,
                                                      float* __restrict__ out) {
  __shared__ bf16 zs[4][16 * DN];     // 4 KB per wave, XOR-swizzled, wave-private
  __shared__ float s_tok[NTOK][DIM];  // used only when gate != 0
  __shared__ float s_c[BM][2];        // used only when gate != 0

  int tid = threadIdx.x, w = tid >> 6, lane = tid & 63;
  int lq = lane >> 4, lr = lane & 15;
  size_t m0 = (size_t)blockIdx.x * BM;
  int srow = w * 16 + lr;                              // this lane's row (s)
  const float* xr = x + (m0 + srow) * DIM + lq * 8;    // per-lane x base
  float g = gate[0];

  float c0 = 0.f, c1 = 0.f;
  if (g != 0.f) {
    int b = (int)(m0 / SX);
    const float* tokb = tokens + (size_t)b * NTOK * DIM;
    for (int i = tid; i < NTOK * DIM; i += 256) ((float*)s_tok)[i] = tokb[i];
    __syncthreads();
    // per-wave: softmax-over-2-tokens coefficients for its 16 rows (gate folded in)
    for (int r = 0; r < 16; ++r) {
      const float* xrow = x + (m0 + w * 16 + r) * DIM;
      float d0 = 0.f, d1 = 0.f;
#pragma unroll
      for (int i = 0; i < 4; ++i) {
        f32x4 v = *(const f32x4*)(xrow + lane * 4 + i * 256);
        f32x4 t0 = *(const f32x4*)(&s_tok[0][lane * 4 + i * 256]);
        f32x4 t1 = *(const f32x4*)(&s_tok[1][lane * 4 + i * 256]);
        d0 += v[0] * t0[0] + v[1] * t0[1] + v[2] * t0[2] + v[3] * t0[3];
        d1 += v[0] * t1[0] + v[1] * t1[1] + v[2] * t1[2] + v[3] * t1[3];
      }
#pragma unroll
      for (int off = 32; off > 0; off >>= 1) {
        d0 += __shfl_xor(d0, off);
        d1 += __shfl_xor(d1, off);
      }
      if (lane == 0) {
        float mm = fmaxf(d0, d1);
        float e0 = expf(d0 - mm), e1 = expf(d1 - mm);
        float inv = g / (e0 + e1);
        s_c[w * 16 + r][0] = e0 * inv;
        s_c[w * 16 + r][1] = e1 * inv;
      }
    }
    // wave-local LDS produce->consume; in-order DS per wave, compiler waits lgkmcnt
    c0 = s_c[srow][0];
    c1 = s_c[srow][1];
  }

  // ---------- GEMM1: Z^T = Wd . x'^T (barrier-free) ----------
  f32x4 acc[8] = {};
  f32x4 cur0 = *(const f32x4*)(xr);
  f32x4 cur1 = *(const f32x4*)(xr + 4);

  if (g == 0.f) {
    for (int kk = 0; kk < DIM - 32; kk += 32) {
      f32x4 nx0 = *(const f32x4*)(xr + kk + 32);   // prefetch next chunk
      f32x4 nx1 = *(const f32x4*)(xr + kk + 36);
      bf16x8 bx;
#pragma unroll
      for (int j = 0; j < 4; ++j) { bx[j] = (bf16)cur0[j]; bx[4 + j] = (bf16)cur1[j]; }
#pragma unroll
      for (int f = 0; f < 8; ++f) {
        bf16x8 wa = *(const bf16x8*)(wdb + (size_t)(f * 16 + lr) * DIM + kk + lq * 8);
        acc[f] = mfma16(wa, bx, acc[f]);
      }
      cur0 = nx0; cur1 = nx1;
    }
    {
      bf16x8 bx;
#pragma unroll
      for (int j = 0; j < 4; ++j) { bx[j] = (bf16)cur0[j]; bx[4 + j] = (bf16)cur1[j]; }
#pragma unroll
      for (int f = 0; f < 8; ++f) {
        bf16x8 wa = *(const bf16x8*)(wdb + (size_t)(f * 16 + lr) * DIM + (DIM - 32) + lq * 8);
        acc[f] = mfma16(wa, bx, acc[f]);
      }
    }
  } else {
    for (int kk = 0; kk < DIM; kk += 32) {
      f32x4 nx0 = cur0, nx1 = cur1;
      if (kk + 32 < DIM) {
        nx0 = *(const f32x4*)(xr + kk + 32);
        nx1 = *(const f32x4*)(xr + kk + 36);
      }
      f32x4 t00 = *(const f32x4*)(&s_tok[0][kk + lq * 8]);
      f32x4 t01 = *(const f32x4*)(&s_tok[0][kk + lq * 8 + 4]);
      f32x4 t10 = *(const f32x4*)(&s_tok[1][kk + lq * 8]);
      f32x4 t11 = *(const f32x4*)(&s_tok[1][kk + lq * 8 + 4]);
      bf16x8 bx;
#pragma unroll
      for (int j = 0; j < 4; ++j) {
        bx[j] = (bf16)(cur0[j] + c0 * t00[j] + c1 * t10[j]);
        bx[4 + j] = (bf16)(cur1[j] + c0 * t01[j] + c1 * t11[j]);
      }
#pragma unroll
      for (int f = 0; f < 8; ++f) {
        bf16x8 wa = *(const bf16x8*)(wdb + (size_t)(f * 16 + lr) * DIM + kk + lq * 8);
        acc[f] = mfma16(wa, bx, acc[f]);
      }
      cur0 = nx0; cur1 = nx1;
    }
  }

  // ---------- ReLU -> bf16 -> wave-private swizzled LDS (no barrier) ----------
  char* zbase = (char*)(&zs[w][0]);
#pragma unroll
  for (int f = 0; f < 8; ++f) {
#pragma unroll
    for (int p = 0; p < 2; ++p) {
      bf16x2 pk;
      pk[0] = (bf16)fmaxf(acc[f][2 * p], 0.f);
      pk[1] = (bf16)fmaxf(acc[f][2 * p + 1], 0.f);
      int dn = f * 16 + lq * 4 + 2 * p;              // Z^T row (dn), pair
      int byte = lr * 256 + ((dn * 2) ^ ((lr & 7) << 4));
      *(bf16x2*)(zbase + byte) = pk;                 // zs[s=lr][dn..dn+1]
    }
  }

  // z-frags for GEMM2: lane reads Z[s=lr][e = t*32 + lq*8 .. +8]
  bf16x8 zf[4];
#pragma unroll
  for (int t = 0; t < 4; ++t) {
    int byte = lr * 256 + (((t * 32 + lq * 8) * 2) ^ ((lr & 7) << 4));
    zf[t] = *(const bf16x8*)(zbase + byte);
  }

  // ---------- GEMM2: out^T = Wu . Z^T (barrier-free, packed stores) ----------
  float* ob = out + (m0 + srow) * ODIM;
#pragma unroll 2
  for (int oc = 0; oc < ODIM / 16; ++oc) {
    f32x4 a2 = {};
#pragma unroll
    for (int t = 0; t < 4; ++t) {
      bf16x8 wf = *(const bf16x8*)(wub + (size_t)(oc * 16 + lr) * DN + t * 32 + lq * 8);
      a2 = mfma16(wf, zf[t], a2);
    }
    *(f32x4*)(ob + oc * 16 + lq * 4) = a2;           // 4 consecutive out cols
  }
}

extern "C" void kernel_launch(void* const* d_in, const int* in_sizes, int n_in,
                              void* d_out, int out_size, void* d_ws, size_t ws_size,
                              hipStream_t stream) {
  const float* x = (const float*)d_in[0];
  const float* y = (const float*)d_in[1];
  const float* lat = (const float*)d_in[2];
  const float* gate = (const float*)d_in[3];
  const float* Wd = (const float*)d_in[4];
  const float* Wu = (const float*)d_in[5];
  float* out = (float*)d_out;
  char* ws = (char*)d_ws;

  float* tokens = (float*)ws;              // 32*2*1024*4   = 262144 B
  bf16* wdb = (bf16*)(ws + 262144);        // 128*1024*2    = 262144 B
  bf16* wub = (bf16*)(ws + 524288);        // 1024*128*2    = 262144 B

  prep_kernel<<<(DN * DIM + 255) / 256, 256, 0, stream>>>(Wd, Wu, wdb, wub);
  tokens_kernel<<<B_N, 256, 0, stream>>>(y, lat, gate, tokens);
  main_kernel<<<(B_N * SX) / BM, 256, 0, stream>>>(x, gate, tokens, wdb, wub, out);
}

// Round 4
// 176.515 us; speedup vs baseline: 1.6796x; 1.6796x over previous
//
#include <hip/hip_runtime.h>
#include <hip/hip_bf16.h>

#define B_N 32
#define SX 2048
#define SY 512
#define DIM 1024
#define NTOK 2
#define DN 128
#define ODIM 1024

#define BM 128
#define BK 64

typedef __bf16 bf16;
typedef __bf16 bf16x8 __attribute__((ext_vector_type(8)));
typedef __bf16 bf16x4 __attribute__((ext_vector_type(4)));
typedef float f32x4 __attribute__((ext_vector_type(4)));

__device__ __forceinline__ f32x4 mfma16(bf16x8 a, bf16x8 b, f32x4 c) {
  return __builtin_amdgcn_mfma_f32_16x16x32_bf16(a, b, c, 0, 0, 0);
}

// Convert weights fp32 -> bf16 once per call (weights are small, L2-resident).
__global__ __launch_bounds__(256) void prep_kernel(const float* __restrict__ Wd,
                                                   const float* __restrict__ Wu,
                                                   bf16* __restrict__ wdb,
                                                   bf16* __restrict__ wub) {
  int i = blockIdx.x * 256 + threadIdx.x;
  if (i < DN * DIM) {
    wdb[i] = (bf16)Wd[i];
    wub[i] = (bf16)Wu[i];
  }
}

// tokens[b,t,:] = latent[t] + sum_s softmax_s(latent[t].y[b,s]) * y[b,s]
// Only needed when gate != 0 (slow path; bench has gate == 0).
__global__ __launch_bounds__(256) void tokens_kernel(const float* __restrict__ y,
                                                     const float* __restrict__ lat,
                                                     const float* __restrict__ gate,
                                                     float* __restrict__ tokens) {
  if (gate[0] == 0.0f) return;  // output is independent of tokens in that case
  __shared__ float s_lat[NTOK][DIM];
  __shared__ float s_sc[NTOK][SY];
  int b = blockIdx.x;
  int tid = threadIdx.x, wave = tid >> 6, lane = tid & 63;
  const float* yb = y + (size_t)b * SY * DIM;
  for (int i = tid; i < NTOK * DIM; i += 256) ((float*)s_lat)[i] = lat[i];
  __syncthreads();
  for (int s = wave * 128; s < wave * 128 + 128; ++s) {
    const float* yr = yb + (size_t)s * DIM;
    float d0 = 0.f, d1 = 0.f;
#pragma unroll
    for (int i = 0; i < 4; ++i) {
      f32x4 v = *(const f32x4*)(yr + lane * 4 + i * 256);
      f32x4 l0 = *(const f32x4*)(&s_lat[0][lane * 4 + i * 256]);
      f32x4 l1 = *(const f32x4*)(&s_lat[1][lane * 4 + i * 256]);
      d0 += v[0] * l0[0] + v[1] * l0[1] + v[2] * l0[2] + v[3] * l0[3];
      d1 += v[0] * l1[0] + v[1] * l1[1] + v[2] * l1[2] + v[3] * l1[3];
    }
#pragma unroll
    for (int off = 32; off > 0; off >>= 1) {
      d0 += __shfl_xor(d0, off);
      d1 += __shfl_xor(d1, off);
    }
    if (lane == 0) { s_sc[0][s] = d0; s_sc[1][s] = d1; }
  }
  __syncthreads();
  if (wave < 2) {
    float m = -3.4e38f;
    for (int s = lane; s < SY; s += 64) m = fmaxf(m, s_sc[wave][s]);
#pragma unroll
    for (int off = 32; off > 0; off >>= 1) m = fmaxf(m, __shfl_xor(m, off));
    float sum = 0.f;
    for (int s = lane; s < SY; s += 64) {
      float e = expf(s_sc[wave][s] - m);
      s_sc[wave][s] = e;
      sum += e;
    }
#pragma unroll
    for (int off = 32; off > 0; off >>= 1) sum += __shfl_xor(sum, off);
    float inv = 1.f / sum;
    for (int s = lane; s < SY; s += 64) s_sc[wave][s] *= inv;
  }
  __syncthreads();
  float a0[4] = {0.f, 0.f, 0.f, 0.f}, a1[4] = {0.f, 0.f, 0.f, 0.f};
  for (int s = 0; s < SY; ++s) {
    float p0 = s_sc[0][s], p1 = s_sc[1][s];
    const float* yr = yb + (size_t)s * DIM;
#pragma unroll
    for (int i = 0; i < 4; ++i) {
      float v = yr[tid + i * 256];
      a0[i] += p0 * v;
      a1[i] += p1 * v;
    }
  }
  float* tb = tokens + (size_t)b * NTOK * DIM;
#pragma unroll
  for (int i = 0; i < 4; ++i) {
    tb[tid + i * 256] = s_lat[0][tid + i * 256] + a0[i];
    tb[DIM + tid + i * 256] = s_lat[1][tid + i * 256] + a1[i];
  }
}

// N-sliced fused kernel: 8 waves, BM=128 rows. Each wave computes ALL 128 rows
// x its own N-slice (16 dn of GEMM1, 128 out-cols of GEMM2), so Wd and Wu are
// each fetched exactly ONCE per block (no per-wave weight duplication).
// x staged in shared LDS (double-buffered, register prefetch, 1 barrier/K-step);
// Z (relu, bf16) in shared LDS aliasing the x buffers.
__global__ __launch_bounds__(512, 4) void main_kernel(const float* __restrict__ x,
                                                      const float* __restrict__ gate,
                                                      const float* __restrict__ tokens,
                                                      const bf16* __restrict__ wdb,
                                                      const bf16* __restrict__ wub,
                                                      float* __restrict__ out) {
  __shared__ union {
    bf16 xs[2][BM][BK];  // 2 x 16 KB, XOR-swizzled
    bf16 zs[BM][DN];     // 32 KB, XOR-swizzled (aliases; barriered)
  } u;
  __shared__ float s_tok[NTOK][DIM];
  __shared__ float s_c[BM][2];

  int tid = threadIdx.x, w = tid >> 6, lane = tid & 63;
  int lq = lane >> 4, lr = lane & 15;
  size_t m0 = (size_t)blockIdx.x * BM;
  const float* xb = x + m0 * DIM;
  float g = gate[0];

  if (g != 0.f) {
    int b = (int)(m0 / SX);
    const float* tokb = tokens + (size_t)b * NTOK * DIM;
    for (int i = tid; i < NTOK * DIM; i += 512) ((float*)s_tok)[i] = tokb[i];
    __syncthreads();
    // per-wave: softmax-over-2-tokens coeffs for its 16 rows (gate folded in)
    for (int i = 0; i < 16; ++i) {
      int r = w * 16 + i;
      const float* xrow = xb + (size_t)r * DIM;
      float d0 = 0.f, d1 = 0.f;
#pragma unroll
      for (int c = 0; c < 4; ++c) {
        f32x4 v = *(const f32x4*)(xrow + lane * 4 + c * 256);
        f32x4 t0 = *(const f32x4*)(&s_tok[0][lane * 4 + c * 256]);
        f32x4 t1 = *(const f32x4*)(&s_tok[1][lane * 4 + c * 256]);
        d0 += v[0] * t0[0] + v[1] * t0[1] + v[2] * t0[2] + v[3] * t0[3];
        d1 += v[0] * t1[0] + v[1] * t1[1] + v[2] * t1[2] + v[3] * t1[3];
      }
#pragma unroll
      for (int off = 32; off > 0; off >>= 1) {
        d0 += __shfl_xor(d0, off);
        d1 += __shfl_xor(d1, off);
      }
      if (lane == 0) {
        float mm = fmaxf(d0, d1);
        float e0 = expf(d0 - mm), e1 = expf(d1 - mm);
        float inv = g / (e0 + e1);
        s_c[r][0] = e0 * inv;
        s_c[r][1] = e1 * inv;
      }
    }
    __syncthreads();
  }

  // staging geometry: idx = tid + it*512 -> row = (tid>>4) + it*32, c4 = tid&15
  int prow = tid >> 4;  // 0..31
  int pc4 = tid & 15;
  char* xsb = (char*)u.xs;

  auto loadpre = [&](f32x4 pre[4], int kcd) {
#pragma unroll
    for (int it = 0; it < 4; ++it) {
      int row = prow + it * 32;
      pre[it] = *(const f32x4*)(xb + (size_t)row * DIM + kcd * BK + pc4 * 4);
    }
  };
  auto stage = [&](char* buf, int kcd, const f32x4 pre[4]) {
    if (g != 0.f) {
      int kbase = kcd * BK + pc4 * 4;
      f32x4 t0 = *(const f32x4*)(&s_tok[0][kbase]);
      f32x4 t1 = *(const f32x4*)(&s_tok[1][kbase]);
#pragma unroll
      for (int it = 0; it < 4; ++it) {
        int row = prow + it * 32;
        float c0 = s_c[row][0], c1 = s_c[row][1];
        bf16x4 o;
#pragma unroll
        for (int j = 0; j < 4; ++j) o[j] = (bf16)(pre[it][j] + c0 * t0[j] + c1 * t1[j]);
        *(bf16x4*)(buf + row * (BK * 2) + ((pc4 * 8) ^ ((row & 7) << 4))) = o;
      }
    } else {
#pragma unroll
      for (int it = 0; it < 4; ++it) {
        int row = prow + it * 32;
        bf16x4 o;
#pragma unroll
        for (int j = 0; j < 4; ++j) o[j] = (bf16)pre[it][j];
        *(bf16x4*)(buf + row * (BK * 2) + ((pc4 * 8) ^ ((row & 7) << 4))) = o;
      }
    }
  };

  // ---------- GEMM1: Z = x' Wd^T ; wave w computes all 128 rows x dn slice ----------
  f32x4 acc1[8] = {};
  const bf16* wdw = wdb + (size_t)(w * 16 + lr) * DIM + lq * 8;  // this lane's Wd row

  f32x4 pre[4];
  loadpre(pre, 0);
  stage(xsb, 0, pre);      // buffer 0 <- kc 0
  loadpre(pre, 1);         // kc 1 in flight across barrier + first MFMA phase
  __syncthreads();

  for (int kc = 0; kc < DIM / BK; ++kc) {
    if (kc + 1 < DIM / BK) {
      stage(xsb + ((kc + 1) & 1) * (BM * BK * 2), kc + 1, pre);  // waits on pre
      if (kc + 2 < DIM / BK) loadpre(pre, kc + 2);               // issue next
    }
    char* buf = xsb + (kc & 1) * (BM * BK * 2);
#pragma unroll
    for (int kk = 0; kk < BK; kk += 32) {
      bf16x8 bw = *(const bf16x8*)(wdw + kc * BK + kk);  // B-frag: Wd[dn=w*16+lr][k]
#pragma unroll
      for (int mt = 0; mt < 8; ++mt) {
        int r = mt * 16 + lr;
        bf16x8 ax = *(const bf16x8*)(buf + r * (BK * 2) + ((2 * (kk + lq * 8)) ^ ((r & 7) << 4)));
        acc1[mt] = mfma16(ax, bw, acc1[mt]);  // D[row][dn-slice]
      }
    }
    __syncthreads();
  }

  // ---------- ReLU -> bf16 Z into LDS (aliases x buffers; barrier after loop protects) ----------
  char* zsb = (char*)u.zs;
#pragma unroll
  for (int mt = 0; mt < 8; ++mt) {
#pragma unroll
    for (int reg = 0; reg < 4; ++reg) {
      int row = mt * 16 + lq * 4 + reg;
      int dn = w * 16 + lr;
      float zv = fmaxf(acc1[mt][reg], 0.f);
      *(bf16*)(zsb + row * (DN * 2) + ((2 * dn) ^ ((row & 7) << 4))) = (bf16)zv;
    }
  }
  __syncthreads();

  // ---------- GEMM2: out = Z Wu^T ; wave w owns out cols [w*128, w*128+128) ----------
  float* ob = out + m0 * ODIM;
#pragma unroll
  for (int half = 0; half < 2; ++half) {
    int oc0 = w * 128 + half * 64;
    bf16x8 bw2[4][4];  // hoisted Wu frags for 64 cols (fetched once per block total)
#pragma unroll
    for (int nt = 0; nt < 4; ++nt)
#pragma unroll
      for (int kkt = 0; kkt < 4; ++kkt)
        bw2[nt][kkt] = *(const bf16x8*)(wub + (size_t)(oc0 + nt * 16 + lr) * DN + kkt * 32 + lq * 8);
#pragma unroll
    for (int mt = 0; mt < 8; ++mt) {
      int r = mt * 16 + lr;
      bf16x8 az[4];
#pragma unroll
      for (int kkt = 0; kkt < 4; ++kkt)
        az[kkt] = *(const bf16x8*)(zsb + r * (DN * 2) + ((2 * (kkt * 32 + lq * 8)) ^ ((r & 7) << 4)));
      f32x4 a2[4] = {};
#pragma unroll
      for (int nt = 0; nt < 4; ++nt)
#pragma unroll
        for (int kkt = 0; kkt < 4; ++kkt)
          a2[nt] = mfma16(az[kkt], bw2[nt][kkt], a2[nt]);
#pragma unroll
      for (int nt = 0; nt < 4; ++nt) {
        int col = oc0 + nt * 16 + lr;
#pragma unroll
        for (int reg = 0; reg < 4; ++reg)
          ob[(size_t)(mt * 16 + lq * 4 + reg) * ODIM + col] = a2[nt][reg];
      }
    }
  }
}

extern "C" void kernel_launch(void* const* d_in, const int* in_sizes, int n_in,
                              void* d_out, int out_size, void* d_ws, size_t ws_size,
                              hipStream_t stream) {
  const float* x = (const float*)d_in[0];
  const float* y = (const float*)d_in[1];
  const float* lat = (const float*)d_in[2];
  const float* gate = (const float*)d_in[3];
  const float* Wd = (const float*)d_in[4];
  const float* Wu = (const float*)d_in[5];
  float* out = (float*)d_out;
  char* ws = (char*)d_ws;

  float* tokens = (float*)ws;              // 32*2*1024*4   = 262144 B
  bf16* wdb = (bf16*)(ws + 262144);        // 128*1024*2    = 262144 B
  bf16* wub = (bf16*)(ws + 524288);        // 1024*128*2    = 262144 B

  prep_kernel<<<(DN * DIM + 255) / 256, 256, 0, stream>>>(Wd, Wu, wdb, wub);
  tokens_kernel<<<B_N, 256, 0, stream>>>(y, lat, gate, tokens);
  main_kernel<<<(B_N * SX) / BM, 512, 0, stream>>>(x, gate, tokens, wdb, wub, out);
}